// Round 17
// baseline (119.331 us; speedup 1.0000x reference)
//
#include <hip/hip_runtime.h>
#include <hip/hip_fp16.h>
#include <math.h>

// LatentVoxelGrid: N=65536 pts, M=131072 voxels, K=8 cand, D=64.
// Factorization: sim pre-activation h[n,c] = HBp[n] + ZC[c] where
//   HBp[n] = f[n]@W1f + p[n]@W1d + b1   (prep GEMM, N rows)
//   ZC[c]  = z[c]@W1z − cen[c]@W1d     (prep GEMM, M rows)
// prep  (cursor=0, z->zbf, fbf, HBp, ZC, stage2 weight B-frags)
// pair  (one wave per point: 8 coalesced ZC rows + relu·w2 dot + softmax + records)
// gather(per-voxel sum -> normalized bf16 msg; msg aliases rec)
// stage2(gate+GRU, B-frags from L2-hot global, LDS = 2KB biases only)

typedef short bf16x8 __attribute__((ext_vector_type(8)));
typedef unsigned short u16x8 __attribute__((ext_vector_type(8)));
typedef float f32x4 __attribute__((ext_vector_type(4)));
#define MFMA __builtin_amdgcn_mfma_f32_16x16x32_bf16
#define CAP 32

__device__ __forceinline__ short f2bf(float f) {  // round-to-nearest-even
  unsigned u = __float_as_uint(f);
  unsigned r = (u + 0x7FFFu + ((u >> 16) & 1u)) >> 16;
  return (short)r;
}

__device__ __forceinline__ float bf2f(unsigned short h) {
  return __uint_as_float(((unsigned)h) << 16);
}

__device__ __forceinline__ float sigm(float x) { return 1.0f / (1.0f + __expf(-x)); }

// ---- prep ----
__global__ __launch_bounds__(256) void prep_kernel(
    const float* __restrict__ z, const float* __restrict__ f,
    const float* __restrict__ pts, const float* __restrict__ centers,
    const float* __restrict__ sim_w1, const float* __restrict__ sim_b1,
    const float* __restrict__ gate_w1, const float* __restrict__ W_ih,
    const float* __restrict__ W_hh,
    unsigned short* __restrict__ zbf, unsigned short* __restrict__ fbf,
    unsigned short* __restrict__ HBp, unsigned short* __restrict__ ZC,
    short* __restrict__ GF, short* __restrict__ WihF, short* __restrict__ WhhF,
    int* __restrict__ cursor, int M)
{
  long tid = (long)blockIdx.x * 256 + threadIdx.x;
  long nthr = (long)gridDim.x * 256;

  for (long i = tid; i < M; i += nthr) cursor[i] = 0;

  long nz = (long)M * 64;
  for (long i = tid * 8; i < nz; i += nthr * 8) {
    float4 a = *(const float4*)&z[i];
    float4 b4 = *(const float4*)&z[i + 4];
    u16x8 o;
    o[0] = (unsigned short)f2bf(a.x);  o[1] = (unsigned short)f2bf(a.y);
    o[2] = (unsigned short)f2bf(a.z);  o[3] = (unsigned short)f2bf(a.w);
    o[4] = (unsigned short)f2bf(b4.x); o[5] = (unsigned short)f2bf(b4.y);
    o[6] = (unsigned short)f2bf(b4.z); o[7] = (unsigned short)f2bf(b4.w);
    *(u16x8*)&zbf[i] = o;
  }

  if (blockIdx.x >= 1024 && blockIdx.x < 1040) {  // stage2 weight B-frags
    int fb = (blockIdx.x - 1024) * 4 + (threadIdx.x >> 6);  // 0..63
    int lane = threadIdx.x & 63, lr = lane & 15, lg = lane >> 4;
    bf16x8 o;
    if (fb < 16) {            // gate_w1 (128,64): frag = ct*4+kt
      int ct = fb >> 2, kt = fb & 3;
#pragma unroll
      for (int e = 0; e < 8; ++e)
        o[e] = f2bf(gate_w1[(kt * 32 + lg * 8 + e) * 64 + ct * 16 + lr]);
      *(bf16x8*)&GF[fb * 512 + lane * 8] = o;
    } else if (fb < 40) {     // W_ih (192,64): frag = g*8 + ct*2 + k2
      int q = fb - 16, g = q >> 3, ct = (q >> 1) & 3, k2 = q & 1;
      int row = g * 64 + ct * 16 + lr;
#pragma unroll
      for (int e = 0; e < 8; ++e)
        o[e] = f2bf(W_ih[row * 64 + k2 * 32 + lg * 8 + e]);
      *(bf16x8*)&WihF[q * 512 + lane * 8] = o;
    } else {                  // W_hh (192,64)
      int q = fb - 40, g = q >> 3, ct = (q >> 1) & 3, k2 = q & 1;
      int row = g * 64 + ct * 16 + lr;
#pragma unroll
      for (int e = 0; e < 8; ++e)
        o[e] = f2bf(W_hh[row * 64 + k2 * 32 + lg * 8 + e]);
      *(bf16x8*)&WhhF[q * 512 + lane * 8] = o;
    }
  }

  // GEMM tasks: g<4096 -> HBp rows (16/task); 4096<=g<12288 -> ZC rows
  int g = blockIdx.x * 4 + (threadIdx.x >> 6);
  int lane = threadIdx.x & 63;
  int lr = lane & 15, lg = lane >> 4;

  if (g < 4096) {            // ---- HBp = f@W1f + p@W1d + b1 ----
    int n0 = g * 16;
    bf16x8 bw[12];           // B: [W1f(64) | W1d(3) | 0], K=96
#pragma unroll
    for (int ct = 0; ct < 4; ++ct) {
#pragma unroll
      for (int kt = 0; kt < 2; ++kt) {
        bf16x8 bb;
#pragma unroll
        for (int e = 0; e < 8; ++e)
          bb[e] = f2bf(sim_w1[(kt * 32 + lg * 8 + e) * 64 + ct * 16 + lr]);
        bw[ct * 3 + kt] = bb;
      }
      bf16x8 bb = {0,0,0,0,0,0,0,0};
#pragma unroll
      for (int e = 0; e < 8; ++e) {
        int kk = lg * 8 + e;
        if (kk < 3) bb[e] = f2bf(sim_w1[(128 + kk) * 64 + ct * 16 + lr]);
      }
      bw[ct * 3 + 2] = bb;
    }

    bf16x8 a[3];
#pragma unroll
    for (int kt = 0; kt < 2; ++kt) {
      const float* src = &f[(long)(n0 + lr) * 64 + kt * 32 + lg * 8];
      float4 v0 = *(const float4*)src;
      float4 v1 = *(const float4*)(src + 4);
      bf16x8 t;
      t[0] = f2bf(v0.x); t[1] = f2bf(v0.y); t[2] = f2bf(v0.z); t[3] = f2bf(v0.w);
      t[4] = f2bf(v1.x); t[5] = f2bf(v1.y); t[6] = f2bf(v1.z); t[7] = f2bf(v1.w);
      a[kt] = t;
    }
    {
      bf16x8 t = {0,0,0,0,0,0,0,0};
      if (lg == 0) {
        t[0] = f2bf(pts[(n0 + lr) * 3 + 0]);
        t[1] = f2bf(pts[(n0 + lr) * 3 + 1]);
        t[2] = f2bf(pts[(n0 + lr) * 3 + 2]);
      }
      a[2] = t;
    }
    *(bf16x8*)&fbf[(long)(n0 + lr) * 64 + lg * 8] = a[0];
    *(bf16x8*)&fbf[(long)(n0 + lr) * 64 + 32 + lg * 8] = a[1];

    f32x4 acc[4] = {{0,0,0,0},{0,0,0,0},{0,0,0,0},{0,0,0,0}};
#pragma unroll
    for (int ct = 0; ct < 4; ++ct)
#pragma unroll
      for (int kt = 0; kt < 3; ++kt)
        acc[ct] = MFMA(a[kt], bw[ct * 3 + kt], acc[ct], 0, 0, 0);

#pragma unroll
    for (int ct = 0; ct < 4; ++ct) {
      float b1 = sim_b1[ct * 16 + lr];
#pragma unroll
      for (int e = 0; e < 4; ++e)
        HBp[(long)(n0 + lg * 4 + e) * 64 + ct * 16 + lr] =
            (unsigned short)f2bf(acc[ct][e] + b1);
    }
  } else if (g < 12288) {    // ---- ZC = z@W1z − cen@W1d ----
    int r0 = (g - 4096) * 16;
    bf16x8 bw[12];           // B: [W1z(64) | W1d(3) | 0], K=96
#pragma unroll
    for (int ct = 0; ct < 4; ++ct) {
#pragma unroll
      for (int kt = 0; kt < 2; ++kt) {
        bf16x8 bb;
#pragma unroll
        for (int e = 0; e < 8; ++e)
          bb[e] = f2bf(sim_w1[(64 + kt * 32 + lg * 8 + e) * 64 + ct * 16 + lr]);
        bw[ct * 3 + kt] = bb;
      }
      bf16x8 bb = {0,0,0,0,0,0,0,0};
#pragma unroll
      for (int e = 0; e < 8; ++e) {
        int kk = lg * 8 + e;
        if (kk < 3) bb[e] = f2bf(sim_w1[(128 + kk) * 64 + ct * 16 + lr]);
      }
      bw[ct * 3 + 2] = bb;
    }

    bf16x8 a[3];
#pragma unroll
    for (int kt = 0; kt < 2; ++kt) {
      const float* src = &z[(long)(r0 + lr) * 64 + kt * 32 + lg * 8];
      float4 v0 = *(const float4*)src;
      float4 v1 = *(const float4*)(src + 4);
      bf16x8 t;
      t[0] = f2bf(v0.x); t[1] = f2bf(v0.y); t[2] = f2bf(v0.z); t[3] = f2bf(v0.w);
      t[4] = f2bf(v1.x); t[5] = f2bf(v1.y); t[6] = f2bf(v1.z); t[7] = f2bf(v1.w);
      a[kt] = t;
    }
    {
      bf16x8 t = {0,0,0,0,0,0,0,0};
      if (lg == 0) {
        t[0] = f2bf(-centers[(r0 + lr) * 3 + 0]);
        t[1] = f2bf(-centers[(r0 + lr) * 3 + 1]);
        t[2] = f2bf(-centers[(r0 + lr) * 3 + 2]);
      }
      a[2] = t;
    }

    f32x4 acc[4] = {{0,0,0,0},{0,0,0,0},{0,0,0,0},{0,0,0,0}};
#pragma unroll
    for (int ct = 0; ct < 4; ++ct)
#pragma unroll
      for (int kt = 0; kt < 3; ++kt)
        acc[ct] = MFMA(a[kt], bw[ct * 3 + kt], acc[ct], 0, 0, 0);

#pragma unroll
    for (int ct = 0; ct < 4; ++ct)
#pragma unroll
      for (int e = 0; e < 4; ++e)
        ZC[(long)(r0 + lg * 4 + e) * 64 + ct * 16 + lr] =
            (unsigned short)f2bf(acc[ct][e]);
  }
}

// ---- pair: one wave per point; no MFMA; coalesced row adds + softmax ----
__global__ __launch_bounds__(256) void pair_kernel(
    const unsigned short* __restrict__ HBp, const unsigned short* __restrict__ ZC,
    const int* __restrict__ cand_idx, const float* __restrict__ sim_w2,
    int* __restrict__ cursor, unsigned* __restrict__ rec)
{
  int n = (blockIdx.x * 256 + threadIdx.x) >> 6;  // point id
  int lane = threadIdx.x & 63;

  int ci = cand_idx[n * 8 + (lane & 7)];
  int c0 = __builtin_amdgcn_readlane(ci, 0);
  int c1 = __builtin_amdgcn_readlane(ci, 1);
  int c2 = __builtin_amdgcn_readlane(ci, 2);
  int c3 = __builtin_amdgcn_readlane(ci, 3);
  int c4 = __builtin_amdgcn_readlane(ci, 4);
  int c5 = __builtin_amdgcn_readlane(ci, 5);
  int c6 = __builtin_amdgcn_readlane(ci, 6);
  int c7 = __builtin_amdgcn_readlane(ci, 7);

  float hbv = bf2f(HBp[(long)n * 64 + lane]);
  float w2 = sim_w2[lane];
  float p0 = fmaxf(hbv + bf2f(ZC[(long)c0 * 64 + lane]), 0.f) * w2;
  float p1 = fmaxf(hbv + bf2f(ZC[(long)c1 * 64 + lane]), 0.f) * w2;
  float p2 = fmaxf(hbv + bf2f(ZC[(long)c2 * 64 + lane]), 0.f) * w2;
  float p3 = fmaxf(hbv + bf2f(ZC[(long)c3 * 64 + lane]), 0.f) * w2;
  float p4 = fmaxf(hbv + bf2f(ZC[(long)c4 * 64 + lane]), 0.f) * w2;
  float p5 = fmaxf(hbv + bf2f(ZC[(long)c5 * 64 + lane]), 0.f) * w2;
  float p6 = fmaxf(hbv + bf2f(ZC[(long)c6 * 64 + lane]), 0.f) * w2;
  float p7 = fmaxf(hbv + bf2f(ZC[(long)c7 * 64 + lane]), 0.f) * w2;

#pragma unroll
  for (int m = 1; m <= 32; m <<= 1) {
    p0 += __shfl_xor(p0, m, 64);
    p1 += __shfl_xor(p1, m, 64);
    p2 += __shfl_xor(p2, m, 64);
    p3 += __shfl_xor(p3, m, 64);
    p4 += __shfl_xor(p4, m, 64);
    p5 += __shfl_xor(p5, m, 64);
    p6 += __shfl_xor(p6, m, 64);
    p7 += __shfl_xor(p7, m, 64);
  }

  // sims uniform across wave; softmax over 8, TAU=0.3
  float mx = fmaxf(fmaxf(fmaxf(p0, p1), fmaxf(p2, p3)),
                   fmaxf(fmaxf(p4, p5), fmaxf(p6, p7)));
  float e0 = __expf((p0 - mx) * (1.0f / 0.3f));
  float e1 = __expf((p1 - mx) * (1.0f / 0.3f));
  float e2 = __expf((p2 - mx) * (1.0f / 0.3f));
  float e3 = __expf((p3 - mx) * (1.0f / 0.3f));
  float e4 = __expf((p4 - mx) * (1.0f / 0.3f));
  float e5 = __expf((p5 - mx) * (1.0f / 0.3f));
  float e6 = __expf((p6 - mx) * (1.0f / 0.3f));
  float e7 = __expf((p7 - mx) * (1.0f / 0.3f));
  float inv = 1.0f / (e0 + e1 + e2 + e3 + e4 + e5 + e6 + e7);

  if (lane < 8) {
    float wsel = lane == 0 ? e0 : lane == 1 ? e1 : lane == 2 ? e2 :
                 lane == 3 ? e3 : lane == 4 ? e4 : lane == 5 ? e5 :
                 lane == 6 ? e6 : e7;
    wsel *= inv;
    int slot = atomicAdd(&cursor[ci], 1);
    if (slot < CAP) {
      unsigned short wh = __half_as_ushort(__float2half(wsel));
      rec[(long)ci * CAP + slot] = ((unsigned)n << 16) | (unsigned)wh;
    }
  }
}

// ---- gather: msg[v] = (Sum w*f[n]) / (Sum w + eps); msg ALIASES rec rows ----
__global__ __launch_bounds__(256) void gather_kernel(
    const unsigned* __restrict__ rec, const int* __restrict__ cursor,
    const unsigned short* __restrict__ fbf, unsigned short* __restrict__ msg_bf,
    int mvox)
{
  int tid = blockIdx.x * 256 + threadIdx.x;
  int row = tid >> 2, seg = tid & 3;  // 4 threads per voxel, 16 cols each
  if (row >= mvox) return;

  int cnt = cursor[row];
  cnt = cnt < CAP ? cnt : CAP;
  const unsigned* rp = &rec[(long)row * CAP];

  float acc[16];
#pragma unroll
  for (int j = 0; j < 16; ++j) acc[j] = 0.f;
  float ws = 0.f;

  for (int i0 = 0; i0 < cnt; i0 += 4) {
    uint4 r4 = *(const uint4*)&rp[i0];
    unsigned rr0 = r4.x, rr1 = r4.y, rr2 = r4.z, rr3 = r4.w;
#pragma unroll
    for (int j = 0; j < 4; ++j) {
      unsigned r = j == 0 ? rr0 : j == 1 ? rr1 : j == 2 ? rr2 : rr3;
      if (i0 + j < cnt) {
        float w = __half2float(__ushort_as_half((unsigned short)(r & 0xffffu)));
        int nn = r >> 16;
        ws += w;
        const u16x8* fp = (const u16x8*)&fbf[(long)nn * 64 + seg * 16];
        u16x8 f0 = fp[0], f1 = fp[1];
#pragma unroll
        for (int k = 0; k < 8; ++k) {
          acc[k]     = fmaf(w, bf2f(f0[k]), acc[k]);
          acc[8 + k] = fmaf(w, bf2f(f1[k]), acc[8 + k]);
        }
      }
    }
  }
  float inv = 1.0f / (ws + 1e-6f);
  u16x8 o0, o1;
#pragma unroll
  for (int j = 0; j < 8; ++j) {
    o0[j] = (unsigned short)f2bf(acc[j] * inv);
    o1[j] = (unsigned short)f2bf(acc[8 + j] * inv);
  }
  *(u16x8*)&msg_bf[(long)row * 64 + seg * 16] = o0;
  *(u16x8*)&msg_bf[(long)row * 64 + seg * 16 + 8] = o1;
}

// ---- Stage 2: gate MLP + GRU; weights as L2-hot global B-frags; LDS=biases ----
__global__ __launch_bounds__(512)
__attribute__((amdgpu_waves_per_eu(2)))
void stage2(
    const unsigned short* __restrict__ zbf,
    const short* __restrict__ GF, const short* __restrict__ WihF,
    const short* __restrict__ WhhF,
    const float* __restrict__ gate_b1, const float* __restrict__ gate_w2,
    const float* __restrict__ gate_b2,
    const float* __restrict__ b_ih, const float* __restrict__ b_hh,
    const unsigned short* __restrict__ msg_bf,
    float* __restrict__ out)
{
  __shared__ float gb1s[64], gw2s[64], bihs[192], bhhs[192];
  __shared__ float gb2s;

  int t = threadIdx.x;
  if (t < 64) { gb1s[t] = gate_b1[t]; gw2s[t] = gate_w2[t]; }
  if (t < 192) { bihs[t] = b_ih[t]; bhhs[t] = b_hh[t]; }
  if (t == 0) gb2s = gate_b2[0];
  __syncthreads();

  int wid = t >> 6, lane = t & 63;
  int lr = lane & 15, lg = lane >> 4;

  int rowbase = blockIdx.x * 128 + wid * 16;
  long abase = (long)(rowbase + lr) * 64;
  bf16x8 a0 = *(const bf16x8*)&zbf[abase + lg * 8];
  bf16x8 a1 = *(const bf16x8*)&zbf[abase + 32 + lg * 8];
  bf16x8 a2 = *(const bf16x8*)&msg_bf[abase + lg * 8];
  bf16x8 a3 = *(const bf16x8*)&msg_bf[abase + 32 + lg * 8];

  // ---- pass 1: gate ----
  f32x4 usum = {0.f, 0.f, 0.f, 0.f};
#pragma unroll 1
  for (int ct = 0; ct < 4; ++ct) {
    f32x4 au = {0, 0, 0, 0};
    au = MFMA(a0, *(const bf16x8*)&GF[(ct * 4 + 0) * 512 + lane * 8], au, 0, 0, 0);
    au = MFMA(a1, *(const bf16x8*)&GF[(ct * 4 + 1) * 512 + lane * 8], au, 0, 0, 0);
    au = MFMA(a2, *(const bf16x8*)&GF[(ct * 4 + 2) * 512 + lane * 8], au, 0, 0, 0);
    au = MFMA(a3, *(const bf16x8*)&GF[(ct * 4 + 3) * 512 + lane * 8], au, 0, 0, 0);
    int c = ct * 16 + lr;
#pragma unroll
    for (int e = 0; e < 4; ++e)
      usum[e] += fmaxf(au[e] + gb1s[c], 0.0f) * gw2s[c];
  }
#pragma unroll
  for (int m = 1; m <= 8; m <<= 1)
#pragma unroll
    for (int e = 0; e < 4; ++e) {
      float v = usum[e];
      usum[e] = v + __shfl_xor(v, m, 64);
    }
  float gate[4];
#pragma unroll
  for (int e = 0; e < 4; ++e) gate[e] = sigm(usum[e] + gb2s);

  // ---- pass 2: GRU, write out per ct ----
#pragma unroll 1
  for (int ct = 0; ct < 4; ++ct) {
    f32x4 air = {0,0,0,0}, aiz = {0,0,0,0}, ain = {0,0,0,0};
    f32x4 ahr = {0,0,0,0}, ahz = {0,0,0,0}, ahn = {0,0,0,0};
#pragma unroll
    for (int k2 = 0; k2 < 2; ++k2) {
      bf16x8 amg = k2 ? a3 : a2;
      bf16x8 az_ = k2 ? a1 : a0;
      int base = ct * 2 + k2;
      air = MFMA(amg, *(const bf16x8*)&WihF[(      base) * 512 + lane * 8], air, 0, 0, 0);
      aiz = MFMA(amg, *(const bf16x8*)&WihF[( 8 +  base) * 512 + lane * 8], aiz, 0, 0, 0);
      ain = MFMA(amg, *(const bf16x8*)&WihF[(16 +  base) * 512 + lane * 8], ain, 0, 0, 0);
      ahr = MFMA(az_, *(const bf16x8*)&WhhF[(      base) * 512 + lane * 8], ahr, 0, 0, 0);
      ahz = MFMA(az_, *(const bf16x8*)&WhhF[( 8 +  base) * 512 + lane * 8], ahz, 0, 0, 0);
      ahn = MFMA(az_, *(const bf16x8*)&WhhF[(16 +  base) * 512 + lane * 8], ahn, 0, 0, 0);
    }
    int c = ct * 16 + lr;
#pragma unroll
    for (int e = 0; e < 4; ++e) {
      float zv = bf2f(zbf[(long)(rowbase + lg * 4 + e) * 64 + c]);
      float rr = sigm(air[e] + bihs[c] + ahr[e] + bhhs[c]);
      float zg = sigm(aiz[e] + bihs[64 + c] + ahz[e] + bhhs[64 + c]);
      float nn = tanhf(ain[e] + bihs[128 + c] + rr * (ahn[e] + bhhs[128 + c]));
      float hnew = (1.0f - zg) * nn + zg * zv;
      out[(long)(rowbase + lg * 4 + e) * 64 + c] = zv + gate[e] * (hnew - zv);
    }
  }
}

extern "C" void kernel_launch(void* const* d_in, const int* in_sizes, int n_in,
                              void* d_out, int out_size, void* d_ws, size_t ws_size,
                              hipStream_t stream) {
  const float* f_pts   = (const float*)d_in[0];
  const float* pts     = (const float*)d_in[1];
  const float* z_lat   = (const float*)d_in[2];
  const float* centers = (const float*)d_in[3];
  const int*   cand    = (const int*)d_in[4];
  const float* sim_w1  = (const float*)d_in[5];
  const float* sim_b1  = (const float*)d_in[6];
  const float* sim_w2  = (const float*)d_in[7];
  // d_in[8] = sim_b2: uniform softmax shift, unused
  const float* gate_w1 = (const float*)d_in[9];
  const float* gate_b1 = (const float*)d_in[10];
  const float* gate_w2 = (const float*)d_in[11];
  const float* gate_b2 = (const float*)d_in[12];
  const float* W_ih    = (const float*)d_in[13];
  const float* W_hh    = (const float*)d_in[14];
  const float* b_ih    = (const float*)d_in[15];
  const float* b_hh    = (const float*)d_in[16];

  int N = in_sizes[0] / 64;
  int M = in_sizes[2] / 64;

  int* cursor = (int*)d_ws;                                        // M i32
  unsigned* rec = (unsigned*)(cursor + M);                         // M*CAP u32
  unsigned short* msg_bf = (unsigned short*)rec;                   // alias: rec consumed by gather
  unsigned short* zbf = (unsigned short*)(rec + (size_t)M * CAP);  // M*64 bf16
  unsigned short* fbf = zbf + (size_t)M * 64;                      // N*64 bf16
  unsigned short* HBp = fbf + (size_t)N * 64;                      // N*64 bf16
  unsigned short* ZC = HBp + (size_t)N * 64;                       // M*64 bf16
  short* GF = (short*)(ZC + (size_t)M * 64);                       // 16*512 bf16
  short* WihF = GF + 16 * 512;                                     // 24*512 bf16
  short* WhhF = WihF + 24 * 512;                                   // 24*512 bf16

  prep_kernel<<<3072, 256, 0, stream>>>(z_lat, f_pts, pts, centers,
                                        sim_w1, sim_b1, gate_w1, W_ih, W_hh,
                                        zbf, fbf, HBp, ZC, GF, WihF, WhhF,
                                        cursor, M);

  pair_kernel<<<N / 4, 256, 0, stream>>>(HBp, ZC, cand, sim_w2, cursor, rec);

  gather_kernel<<<(M * 4) / 256, 256, 0, stream>>>(rec, cursor, fbf, msg_bf, M);

  stage2<<<M / 128, 512, 0, stream>>>(zbf, GF, WihF, WhhF,
                                      gate_b1, gate_w2, gate_b2, b_ih, b_hh,
                                      msg_bf, (float*)d_out);
}

// Round 18
// 102.403 us; speedup vs baseline: 1.1653x; 1.1653x over previous
//
#include <hip/hip_runtime.h>
#include <hip/hip_fp16.h>
#include <math.h>

// LatentVoxelGrid: N=65536 pts, M=131072 voxels, K=8 cand, D=64.
// Factorization: sim pre-activation h[n,c] = HBp[n] + ZC[c] where
//   HBp[n] = f[n]@W1f + p[n]@W1d + b1   (prep GEMM, N rows)
//   ZC[c]  = z[c]@W1z − cen[c]@W1d      (prep GEMM, M rows; also emits zbf)
// prep0 (cursor=0 + ALL weight B-frag packs)
// prep  (HBp GEMM + fbf; ZC GEMM + zbf; frags loaded coalesced)
// pair  (lane=(cand,colgroup): 1 ZC dwordx4/lane, 9 shfls total, records)
// gather(per-voxel sum -> normalized bf16 msg; msg aliases rec)
// stage2(gate+GRU, B-frags from L2-hot global, LDS = 2KB biases only)

typedef short bf16x8 __attribute__((ext_vector_type(8)));
typedef unsigned short u16x8 __attribute__((ext_vector_type(8)));
typedef float f32x4 __attribute__((ext_vector_type(4)));
#define MFMA __builtin_amdgcn_mfma_f32_16x16x32_bf16
#define CAP 32

__device__ __forceinline__ short f2bf(float f) {  // round-to-nearest-even
  unsigned u = __float_as_uint(f);
  unsigned r = (u + 0x7FFFu + ((u >> 16) & 1u)) >> 16;
  return (short)r;
}

__device__ __forceinline__ float bf2f(unsigned short h) {
  return __uint_as_float(((unsigned)h) << 16);
}

__device__ __forceinline__ float sigm(float x) { return 1.0f / (1.0f + __expf(-x)); }

// ---- prep0: cursor=0 + pack all weight fragments ----
__global__ __launch_bounds__(256) void prep0_kernel(
    const float* __restrict__ sim_w1, const float* __restrict__ gate_w1,
    const float* __restrict__ W_ih, const float* __restrict__ W_hh,
    short* __restrict__ bfF, short* __restrict__ bfZC,
    short* __restrict__ GF, short* __restrict__ WihF, short* __restrict__ WhhF,
    int* __restrict__ cursor, int M)
{
  int tid = blockIdx.x * 256 + threadIdx.x;
  int n4 = M >> 2;
  int stride = gridDim.x * 256;
  int4* cp = (int4*)cursor;
  for (int j = tid; j < n4; j += stride) cp[j] = make_int4(0, 0, 0, 0);

  int w = blockIdx.x * 4 + (threadIdx.x >> 6);  // wave-task 0..127
  int lane = threadIdx.x & 63, lr = lane & 15, lg = lane >> 4;
  bf16x8 o;

  if (w < 12) {            // bfF: [W1f(64) | W1d(3) | 0], frag = ct*3+kt
    int ct = w / 3, kt = w % 3;
#pragma unroll
    for (int e = 0; e < 8; ++e) {
      int k = kt * 32 + lg * 8 + e;
      float v = 0.0f;
      if (kt < 2) v = sim_w1[k * 64 + ct * 16 + lr];
      else if ((k - 64) < 3) v = sim_w1[(128 + (k - 64)) * 64 + ct * 16 + lr];
      o[e] = f2bf(v);
    }
    *(bf16x8*)&bfF[w * 512 + lane * 8] = o;
  } else if (w < 24) {     // bfZC: [W1z(64) | W1d(3) | 0]
    int q = w - 12, ct = q / 3, kt = q % 3;
#pragma unroll
    for (int e = 0; e < 8; ++e) {
      int k = kt * 32 + lg * 8 + e;
      float v = 0.0f;
      if (kt < 2) v = sim_w1[(64 + k) * 64 + ct * 16 + lr];
      else if ((k - 64) < 3) v = sim_w1[(128 + (k - 64)) * 64 + ct * 16 + lr];
      o[e] = f2bf(v);
    }
    *(bf16x8*)&bfZC[q * 512 + lane * 8] = o;
  } else if (w < 40) {     // GF: gate_w1 (128,64), frag = ct*4+kt
    int q = w - 24, ct = q >> 2, kt = q & 3;
#pragma unroll
    for (int e = 0; e < 8; ++e)
      o[e] = f2bf(gate_w1[(kt * 32 + lg * 8 + e) * 64 + ct * 16 + lr]);
    *(bf16x8*)&GF[q * 512 + lane * 8] = o;
  } else if (w < 64) {     // WihF: W_ih (192,64), frag = g*8 + ct*2 + k2
    int q = w - 40, g = q >> 3, ct = (q >> 1) & 3, k2 = q & 1;
    int row = g * 64 + ct * 16 + lr;
#pragma unroll
    for (int e = 0; e < 8; ++e)
      o[e] = f2bf(W_ih[row * 64 + k2 * 32 + lg * 8 + e]);
    *(bf16x8*)&WihF[q * 512 + lane * 8] = o;
  } else if (w < 88) {     // WhhF: W_hh (192,64)
    int q = w - 64, g = q >> 3, ct = (q >> 1) & 3, k2 = q & 1;
    int row = g * 64 + ct * 16 + lr;
#pragma unroll
    for (int e = 0; e < 8; ++e)
      o[e] = f2bf(W_hh[row * 64 + k2 * 32 + lg * 8 + e]);
    *(bf16x8*)&WhhF[q * 512 + lane * 8] = o;
  }
}

// ---- prep: HBp GEMM (+fbf), ZC GEMM (+zbf); frags coalesced ----
__global__ __launch_bounds__(256) void prep_kernel(
    const float* __restrict__ z, const float* __restrict__ f,
    const float* __restrict__ pts, const float* __restrict__ centers,
    const float* __restrict__ sim_b1,
    const short* __restrict__ bfF, const short* __restrict__ bfZC,
    unsigned short* __restrict__ zbf, unsigned short* __restrict__ fbf,
    unsigned short* __restrict__ HBp, unsigned short* __restrict__ ZC)
{
  int g = blockIdx.x * 4 + (threadIdx.x >> 6);
  int lane = threadIdx.x & 63;
  int lr = lane & 15, lg = lane >> 4;

  if (g < 4096) {            // ---- HBp = f@W1f + p@W1d + b1; emit fbf ----
    int n0 = g * 16;
    bf16x8 bw[12];
#pragma unroll
    for (int i = 0; i < 12; ++i) bw[i] = *(const bf16x8*)&bfF[i * 512 + lane * 8];

    bf16x8 a[3];
#pragma unroll
    for (int kt = 0; kt < 2; ++kt) {
      const float* src = &f[(long)(n0 + lr) * 64 + kt * 32 + lg * 8];
      float4 v0 = *(const float4*)src;
      float4 v1 = *(const float4*)(src + 4);
      bf16x8 t;
      t[0] = f2bf(v0.x); t[1] = f2bf(v0.y); t[2] = f2bf(v0.z); t[3] = f2bf(v0.w);
      t[4] = f2bf(v1.x); t[5] = f2bf(v1.y); t[6] = f2bf(v1.z); t[7] = f2bf(v1.w);
      a[kt] = t;
    }
    {
      bf16x8 t = {0,0,0,0,0,0,0,0};
      if (lg == 0) {
        t[0] = f2bf(pts[(n0 + lr) * 3 + 0]);
        t[1] = f2bf(pts[(n0 + lr) * 3 + 1]);
        t[2] = f2bf(pts[(n0 + lr) * 3 + 2]);
      }
      a[2] = t;
    }
    *(bf16x8*)&fbf[(long)(n0 + lr) * 64 + lg * 8] = a[0];
    *(bf16x8*)&fbf[(long)(n0 + lr) * 64 + 32 + lg * 8] = a[1];

    f32x4 acc[4] = {{0,0,0,0},{0,0,0,0},{0,0,0,0},{0,0,0,0}};
#pragma unroll
    for (int ct = 0; ct < 4; ++ct)
#pragma unroll
      for (int kt = 0; kt < 3; ++kt)
        acc[ct] = MFMA(a[kt], bw[ct * 3 + kt], acc[ct], 0, 0, 0);

#pragma unroll
    for (int ct = 0; ct < 4; ++ct) {
      float b1 = sim_b1[ct * 16 + lr];
#pragma unroll
      for (int e = 0; e < 4; ++e)
        HBp[(long)(n0 + lg * 4 + e) * 64 + ct * 16 + lr] =
            (unsigned short)f2bf(acc[ct][e] + b1);
    }
  } else if (g < 12288) {    // ---- ZC = z@W1z − cen@W1d; emit zbf ----
    int r0 = (g - 4096) * 16;
    bf16x8 bw[12];
#pragma unroll
    for (int i = 0; i < 12; ++i) bw[i] = *(const bf16x8*)&bfZC[i * 512 + lane * 8];

    bf16x8 a[3];
#pragma unroll
    for (int kt = 0; kt < 2; ++kt) {
      const float* src = &z[(long)(r0 + lr) * 64 + kt * 32 + lg * 8];
      float4 v0 = *(const float4*)src;
      float4 v1 = *(const float4*)(src + 4);
      bf16x8 t;
      t[0] = f2bf(v0.x); t[1] = f2bf(v0.y); t[2] = f2bf(v0.z); t[3] = f2bf(v0.w);
      t[4] = f2bf(v1.x); t[5] = f2bf(v1.y); t[6] = f2bf(v1.z); t[7] = f2bf(v1.w);
      a[kt] = t;
    }
    {
      bf16x8 t = {0,0,0,0,0,0,0,0};
      if (lg == 0) {
        t[0] = f2bf(-centers[(r0 + lr) * 3 + 0]);
        t[1] = f2bf(-centers[(r0 + lr) * 3 + 1]);
        t[2] = f2bf(-centers[(r0 + lr) * 3 + 2]);
      }
      a[2] = t;
    }
    *(bf16x8*)&zbf[(long)(r0 + lr) * 64 + lg * 8] = a[0];
    *(bf16x8*)&zbf[(long)(r0 + lr) * 64 + 32 + lg * 8] = a[1];

    f32x4 acc[4] = {{0,0,0,0},{0,0,0,0},{0,0,0,0},{0,0,0,0}};
#pragma unroll
    for (int ct = 0; ct < 4; ++ct)
#pragma unroll
      for (int kt = 0; kt < 3; ++kt)
        acc[ct] = MFMA(a[kt], bw[ct * 3 + kt], acc[ct], 0, 0, 0);

#pragma unroll
    for (int ct = 0; ct < 4; ++ct)
#pragma unroll
      for (int e = 0; e < 4; ++e)
        ZC[(long)(r0 + lg * 4 + e) * 64 + ct * 16 + lr] =
            (unsigned short)f2bf(acc[ct][e]);
  }
}

// ---- pair: lane = (cand k=lane&7, colgroup g=lane>>3); 9 shfls total ----
__global__ __launch_bounds__(256) void pair_kernel(
    const unsigned short* __restrict__ HBp, const unsigned short* __restrict__ ZC,
    const int* __restrict__ cand_idx, const float* __restrict__ sim_w2,
    int* __restrict__ cursor, unsigned* __restrict__ rec)
{
  int n = (blockIdx.x * 256 + threadIdx.x) >> 6;  // point id
  int lane = threadIdx.x & 63;
  int k = lane & 7, cg = lane >> 3;

  int ci = cand_idx[n * 8 + k];

  // this lane: candidate ci, columns cg*8 .. cg*8+7
  uint4 zc4 = *(const uint4*)&ZC[(long)ci * 64 + cg * 8];
  uint4 hb4 = *(const uint4*)&HBp[(long)n * 64 + cg * 8];
  float4 w2a = *(const float4*)&sim_w2[cg * 8];
  float4 w2b = *(const float4*)&sim_w2[cg * 8 + 4];

  float s = 0.f;
  {
    unsigned zd[4] = {zc4.x, zc4.y, zc4.z, zc4.w};
    unsigned hd[4] = {hb4.x, hb4.y, hb4.z, hb4.w};
    float w2v[8] = {w2a.x, w2a.y, w2a.z, w2a.w, w2b.x, w2b.y, w2b.z, w2b.w};
#pragma unroll
    for (int d = 0; d < 4; ++d) {
      float zlo = __uint_as_float(zd[d] << 16);
      float zhi = __uint_as_float(zd[d] & 0xffff0000u);
      float hlo = __uint_as_float(hd[d] << 16);
      float hhi = __uint_as_float(hd[d] & 0xffff0000u);
      s = fmaf(fmaxf(hlo + zlo, 0.f), w2v[2 * d], s);
      s = fmaf(fmaxf(hhi + zhi, 0.f), w2v[2 * d + 1], s);
    }
  }

  // sum over the 8 col-groups (stride-8 lanes share k)
#pragma unroll
  for (int m = 8; m <= 32; m <<= 1) s += __shfl_xor(s, m, 64);
  // s = sims[k] (replicated across cg)

  // softmax over the 8 candidates (xor 1,2,4 spans k)
  float mx = s;
#pragma unroll
  for (int m = 1; m <= 4; m <<= 1) mx = fmaxf(mx, __shfl_xor(mx, m, 64));
  float e = __expf((s - mx) * (1.0f / 0.3f));
  float ss = e;
#pragma unroll
  for (int m = 1; m <= 4; m <<= 1) ss += __shfl_xor(ss, m, 64);
  float w = e / ss;

  if (lane < 8) {
    int slot = atomicAdd(&cursor[ci], 1);
    if (slot < CAP) {
      unsigned short wh = __half_as_ushort(__float2half(w));
      rec[(long)ci * CAP + slot] = ((unsigned)n << 16) | (unsigned)wh;
    }
  }
}

// ---- gather: msg[v] = (Sum w*f[n]) / (Sum w + eps); msg ALIASES rec rows ----
__global__ __launch_bounds__(256) void gather_kernel(
    const unsigned* __restrict__ rec, const int* __restrict__ cursor,
    const unsigned short* __restrict__ fbf, unsigned short* __restrict__ msg_bf,
    int mvox)
{
  int tid = blockIdx.x * 256 + threadIdx.x;
  int row = tid >> 2, seg = tid & 3;  // 4 threads per voxel, 16 cols each
  if (row >= mvox) return;

  int cnt = cursor[row];
  cnt = cnt < CAP ? cnt : CAP;
  const unsigned* rp = &rec[(long)row * CAP];

  float acc[16];
#pragma unroll
  for (int j = 0; j < 16; ++j) acc[j] = 0.f;
  float ws = 0.f;

  for (int i0 = 0; i0 < cnt; i0 += 4) {
    uint4 r4 = *(const uint4*)&rp[i0];
    unsigned rr0 = r4.x, rr1 = r4.y, rr2 = r4.z, rr3 = r4.w;
#pragma unroll
    for (int j = 0; j < 4; ++j) {
      unsigned r = j == 0 ? rr0 : j == 1 ? rr1 : j == 2 ? rr2 : rr3;
      if (i0 + j < cnt) {
        float w = __half2float(__ushort_as_half((unsigned short)(r & 0xffffu)));
        int nn = r >> 16;
        ws += w;
        const u16x8* fp = (const u16x8*)&fbf[(long)nn * 64 + seg * 16];
        u16x8 f0 = fp[0], f1 = fp[1];
#pragma unroll
        for (int kk = 0; kk < 8; ++kk) {
          acc[kk]     = fmaf(w, bf2f(f0[kk]), acc[kk]);
          acc[8 + kk] = fmaf(w, bf2f(f1[kk]), acc[8 + kk]);
        }
      }
    }
  }
  float inv = 1.0f / (ws + 1e-6f);
  u16x8 o0, o1;
#pragma unroll
  for (int j = 0; j < 8; ++j) {
    o0[j] = (unsigned short)f2bf(acc[j] * inv);
    o1[j] = (unsigned short)f2bf(acc[8 + j] * inv);
  }
  *(u16x8*)&msg_bf[(long)row * 64 + seg * 16] = o0;
  *(u16x8*)&msg_bf[(long)row * 64 + seg * 16 + 8] = o1;
}

// ---- Stage 2: gate MLP + GRU; weights as L2-hot global B-frags; LDS=biases ----
__global__ __launch_bounds__(512)
__attribute__((amdgpu_waves_per_eu(2)))
void stage2(
    const unsigned short* __restrict__ zbf,
    const short* __restrict__ GF, const short* __restrict__ WihF,
    const short* __restrict__ WhhF,
    const float* __restrict__ gate_b1, const float* __restrict__ gate_w2,
    const float* __restrict__ gate_b2,
    const float* __restrict__ b_ih, const float* __restrict__ b_hh,
    const unsigned short* __restrict__ msg_bf,
    float* __restrict__ out)
{
  __shared__ float gb1s[64], gw2s[64], bihs[192], bhhs[192];
  __shared__ float gb2s;

  int t = threadIdx.x;
  if (t < 64) { gb1s[t] = gate_b1[t]; gw2s[t] = gate_w2[t]; }
  if (t < 192) { bihs[t] = b_ih[t]; bhhs[t] = b_hh[t]; }
  if (t == 0) gb2s = gate_b2[0];
  __syncthreads();

  int wid = t >> 6, lane = t & 63;
  int lr = lane & 15, lg = lane >> 4;

  int rowbase = blockIdx.x * 128 + wid * 16;
  long abase = (long)(rowbase + lr) * 64;
  bf16x8 a0 = *(const bf16x8*)&zbf[abase + lg * 8];
  bf16x8 a1 = *(const bf16x8*)&zbf[abase + 32 + lg * 8];
  bf16x8 a2 = *(const bf16x8*)&msg_bf[abase + lg * 8];
  bf16x8 a3 = *(const bf16x8*)&msg_bf[abase + 32 + lg * 8];

  // ---- pass 1: gate ----
  f32x4 usum = {0.f, 0.f, 0.f, 0.f};
#pragma unroll 1
  for (int ct = 0; ct < 4; ++ct) {
    f32x4 au = {0, 0, 0, 0};
    au = MFMA(a0, *(const bf16x8*)&GF[(ct * 4 + 0) * 512 + lane * 8], au, 0, 0, 0);
    au = MFMA(a1, *(const bf16x8*)&GF[(ct * 4 + 1) * 512 + lane * 8], au, 0, 0, 0);
    au = MFMA(a2, *(const bf16x8*)&GF[(ct * 4 + 2) * 512 + lane * 8], au, 0, 0, 0);
    au = MFMA(a3, *(const bf16x8*)&GF[(ct * 4 + 3) * 512 + lane * 8], au, 0, 0, 0);
    int c = ct * 16 + lr;
#pragma unroll
    for (int e = 0; e < 4; ++e)
      usum[e] += fmaxf(au[e] + gb1s[c], 0.0f) * gw2s[c];
  }
#pragma unroll
  for (int m = 1; m <= 8; m <<= 1)
#pragma unroll
    for (int e = 0; e < 4; ++e) {
      float v = usum[e];
      usum[e] = v + __shfl_xor(v, m, 64);
    }
  float gate[4];
#pragma unroll
  for (int e = 0; e < 4; ++e) gate[e] = sigm(usum[e] + gb2s);

  // ---- pass 2: GRU, write out per ct ----
#pragma unroll 1
  for (int ct = 0; ct < 4; ++ct) {
    f32x4 air = {0,0,0,0}, aiz = {0,0,0,0}, ain = {0,0,0,0};
    f32x4 ahr = {0,0,0,0}, ahz = {0,0,0,0}, ahn = {0,0,0,0};
#pragma unroll
    for (int k2 = 0; k2 < 2; ++k2) {
      bf16x8 amg = k2 ? a3 : a2;
      bf16x8 az_ = k2 ? a1 : a0;
      int base = ct * 2 + k2;
      air = MFMA(amg, *(const bf16x8*)&WihF[(      base) * 512 + lane * 8], air, 0, 0, 0);
      aiz = MFMA(amg, *(const bf16x8*)&WihF[( 8 +  base) * 512 + lane * 8], aiz, 0, 0, 0);
      ain = MFMA(amg, *(const bf16x8*)&WihF[(16 +  base) * 512 + lane * 8], ain, 0, 0, 0);
      ahr = MFMA(az_, *(const bf16x8*)&WhhF[(      base) * 512 + lane * 8], ahr, 0, 0, 0);
      ahz = MFMA(az_, *(const bf16x8*)&WhhF[( 8 +  base) * 512 + lane * 8], ahz, 0, 0, 0);
      ahn = MFMA(az_, *(const bf16x8*)&WhhF[(16 +  base) * 512 + lane * 8], ahn, 0, 0, 0);
    }
    int c = ct * 16 + lr;
#pragma unroll
    for (int e = 0; e < 4; ++e) {
      float zv = bf2f(zbf[(long)(rowbase + lg * 4 + e) * 64 + c]);
      float rr = sigm(air[e] + bihs[c] + ahr[e] + bhhs[c]);
      float zg = sigm(aiz[e] + bihs[64 + c] + ahz[e] + bhhs[64 + c]);
      float nn = tanhf(ain[e] + bihs[128 + c] + rr * (ahn[e] + bhhs[128 + c]));
      float hnew = (1.0f - zg) * nn + zg * zv;
      out[(long)(rowbase + lg * 4 + e) * 64 + c] = zv + gate[e] * (hnew - zv);
    }
  }
}

extern "C" void kernel_launch(void* const* d_in, const int* in_sizes, int n_in,
                              void* d_out, int out_size, void* d_ws, size_t ws_size,
                              hipStream_t stream) {
  const float* f_pts   = (const float*)d_in[0];
  const float* pts     = (const float*)d_in[1];
  const float* z_lat   = (const float*)d_in[2];
  const float* centers = (const float*)d_in[3];
  const int*   cand    = (const int*)d_in[4];
  const float* sim_w1  = (const float*)d_in[5];
  const float* sim_b1  = (const float*)d_in[6];
  const float* sim_w2  = (const float*)d_in[7];
  // d_in[8] = sim_b2: uniform softmax shift, unused
  const float* gate_w1 = (const float*)d_in[9];
  const float* gate_b1 = (const float*)d_in[10];
  const float* gate_w2 = (const float*)d_in[11];
  const float* gate_b2 = (const float*)d_in[12];
  const float* W_ih    = (const float*)d_in[13];
  const float* W_hh    = (const float*)d_in[14];
  const float* b_ih    = (const float*)d_in[15];
  const float* b_hh    = (const float*)d_in[16];

  int N = in_sizes[0] / 64;
  int M = in_sizes[2] / 64;

  int* cursor = (int*)d_ws;                                        // M i32
  unsigned* rec = (unsigned*)(cursor + M);                         // M*CAP u32
  unsigned short* msg_bf = (unsigned short*)rec;                   // alias: rec consumed by gather
  unsigned short* zbf = (unsigned short*)(rec + (size_t)M * CAP);  // M*64 bf16
  unsigned short* fbf = zbf + (size_t)M * 64;                      // N*64 bf16
  unsigned short* HBp = fbf + (size_t)N * 64;                      // N*64 bf16
  unsigned short* ZC = HBp + (size_t)N * 64;                       // M*64 bf16
  short* bfF = (short*)(ZC + (size_t)M * 64);                      // 12*512 bf16
  short* bfZC = bfF + 12 * 512;                                    // 12*512 bf16
  short* GF = bfZC + 12 * 512;                                     // 16*512 bf16
  short* WihF = GF + 16 * 512;                                     // 24*512 bf16
  short* WhhF = WihF + 24 * 512;                                   // 24*512 bf16

  prep0_kernel<<<32, 256, 0, stream>>>(sim_w1, gate_w1, W_ih, W_hh,
                                       bfF, bfZC, GF, WihF, WhhF, cursor, M);

  prep_kernel<<<3072, 256, 0, stream>>>(z_lat, f_pts, pts, centers, sim_b1,
                                        bfF, bfZC, zbf, fbf, HBp, ZC);

  pair_kernel<<<N / 4, 256, 0, stream>>>(HBp, ZC, cand, sim_w2, cursor, rec);

  gather_kernel<<<(M * 4) / 256, 256, 0, stream>>>(rec, cursor, fbf, msg_bf, M);

  stage2<<<M / 128, 512, 0, stream>>>(zbf, GF, WihF, WhhF,
                                      gate_b1, gate_w2, gate_b2, b_ih, b_hh,
                                      msg_bf, (float*)d_out);
}